// Round 3
// baseline (394.688 us; speedup 1.0000x reference)
//
#include <hip/hip_runtime.h>
#include <hip/hip_bf16.h>
#include <stdint.h>
#include <stddef.h>

#define DIMV 2048
#define CTXV 512
#define BV   8192
#define NPV  512
#define NSV  256

typedef __attribute__((ext_vector_type(8))) __bf16 bf16x8;
typedef __attribute__((ext_vector_type(4))) __bf16 bf16x4;
typedef __attribute__((ext_vector_type(4))) float f32x4;

enum { EPI_BIAS = 0, EPI_RELU = 1, EPI_SUBR = 2 };

__device__ __forceinline__ void gload_lds16(const void* g, void* l) {
    __builtin_amdgcn_global_load_lds(
        (const __attribute__((address_space(1))) unsigned int*)g,
        (__attribute__((address_space(3))) unsigned int*)l,
        16, 0, 0);
}

// ---------------------------------------------------------------------------
// Batched fp32 -> bf16 convert (x, ctx, 9 weights)
// ---------------------------------------------------------------------------
struct CvtArgs {
    const float* src[11];
    __bf16*      dst[11];
};

__global__ __launch_bounds__(256) void cvt_all(CvtArgs a) {
    constexpr int NSEG = 11;
    constexpr unsigned cum[NSEG + 1] = {
        0u, 2097152u, 2621440u, 2752512u, 2883584u, 3014656u,
        3080192u, 3145728u, 3153920u, 3284992u, 3416064u, 3481600u};
    const unsigned total = cum[NSEG];
    for (unsigned c = blockIdx.x * blockDim.x + threadIdx.x; c < total;
         c += gridDim.x * blockDim.x) {
        const float* sp = a.src[0];
        __bf16*      dp = a.dst[0];
        unsigned     base = 0;
#pragma unroll
        for (int t = 1; t < NSEG; ++t) {
            const bool g = (c >= cum[t]);
            sp   = g ? a.src[t] : sp;
            dp   = g ? a.dst[t] : dp;
            base = g ? cum[t] : base;
        }
        const unsigned off = (c - base) * 8u;
        f32x4 v0 = *(const f32x4*)(sp + off);
        f32x4 v1 = *(const f32x4*)(sp + off + 4);
        bf16x8 o;
#pragma unroll
        for (int e = 0; e < 4; ++e) { o[e] = (__bf16)v0[e]; o[e + 4] = (__bf16)v1[e]; }
        *(bf16x8*)(dp + off) = o;
    }
}

// ---------------------------------------------------------------------------
// Shared GEMM machinery. 128x128 tile, BK=32, 4 waves (2x2), 16x16x32 MFMA.
// global_load_lds(16B) into linear LDS; read-side XOR swizzle (chunk ^=
// (row>>1)&3) realized by pre-swizzling the GLOBAL source address.
// MFMA operands SWAPPED: acc[i][j] = mfma(bfr[j], af[i], acc) so each lane's
// 4 acc regs are 4 CONSECUTIVE OUTPUT COLS -> float4/bf16x4 epilogues.
//   batch row  = m0 + wr*64 + i*16 + (lane&15)
//   out col    = n0 + wc*64 + j*16 + (lane>>4)*4 + r
// ---------------------------------------------------------------------------
#define GEMM_PREAMBLE(NBX)                                        \
    __shared__ __align__(16) __bf16 ldsA[128 * 32];               \
    __shared__ __align__(16) __bf16 ldsB[128 * 32];               \
    char* ldsAb = (char*)ldsA;                                    \
    char* ldsBb = (char*)ldsB;                                    \
    const int nwg = gridDim.x;                                    \
    const int bid = blockIdx.x;                                   \
    const int wg  = (bid & 7) * (nwg >> 3) + (bid >> 3);          \
    const int bx  = wg % (NBX);                                   \
    const int by  = wg / (NBX);                                   \
    const int m0  = bx * 128;                                     \
    const int n0  = by * 128;                                     \
    const int tid  = threadIdx.x;                                 \
    const int wave = tid >> 6;                                    \
    const int lane = tid & 63;                                    \
    const int lhi  = lane >> 4;                                   \
    const int llo  = lane & 15;                                   \
    const int wr   = wave >> 1;                                   \
    const int wc   = wave & 1;                                    \
    const int rins = lane >> 2;                                   \
    const int ch   = lane & 3;

#define STAGE_TILE(Asrc, ldA, Wsrc, ldW, kofs)                                    \
    _Pragma("unroll")                                                             \
    for (int half = 0; half < 2; ++half) {                                        \
        const int rt = wave * 32 + half * 16 + rins;                              \
        const int kc = ch ^ ((rt >> 1) & 3);                                      \
        const int kk = (kofs) + kc * 8;                                           \
        gload_lds16((Asrc) + (size_t)(m0 + rt) * (ldA) + kk,                      \
                    ldsAb + wave * 2048 + half * 1024);                           \
        gload_lds16((Wsrc) + (size_t)(n0r + rt) * (ldW) + kk,                     \
                    ldsBb + wave * 2048 + half * 1024);                           \
    }

#define LOAD_FRAGS(af, bfr)                                       \
    _Pragma("unroll")                                             \
    for (int i = 0; i < 4; ++i) {                                 \
        const int r  = wr * 64 + i * 16 + llo;                    \
        const int pc = lhi ^ ((r >> 1) & 3);                      \
        af[i] = *(const bf16x8*)(ldsAb + r * 64 + pc * 16);       \
    }                                                             \
    _Pragma("unroll")                                             \
    for (int j = 0; j < 4; ++j) {                                 \
        const int r  = wc * 64 + j * 16 + llo;                    \
        const int pc = lhi ^ ((r >> 1) & 3);                      \
        bfr[j] = *(const bf16x8*)(ldsBb + r * 64 + pc * 16);      \
    }

template <int EPI>
__global__ __launch_bounds__(256)
void pe_gemm(const __bf16* __restrict__ A, int ldA,
             const __bf16* __restrict__ W1, const __bf16* __restrict__ W2,
             int ldW, int NB1, int N1cols, int N2cols, int K, int nbx,
             const float* __restrict__ bias,
             const __bf16* __restrict__ subp,
             __bf16* __restrict__ out1, __bf16* __restrict__ out2)
{
    GEMM_PREAMBLE(nbx)

    // N-region resolve (block-uniform; NB1 multiple of 128)
    const bool reg2   = (W2 != nullptr) && (n0 >= NB1);
    const __bf16* Wa  = reg2 ? W2 : W1;
    const int n0r     = reg2 ? (n0 - NB1) : n0;
    __bf16* outp      = reg2 ? out2 : out1;
    const int ldo     = reg2 ? N2cols : N1cols;

    const f32x4 fzero = {0.f, 0.f, 0.f, 0.f};
    f32x4 acc[4][4];
#pragma unroll
    for (int i = 0; i < 4; ++i)
#pragma unroll
        for (int j = 0; j < 4; ++j) acc[i][j] = fzero;

    for (int k0 = 0; k0 < K; k0 += 32) {
        __syncthreads();
        STAGE_TILE(A, ldA, Wa, ldW, k0)
        __syncthreads();
        bf16x8 af[4], bfr[4];
        LOAD_FRAGS(af, bfr)
#pragma unroll
        for (int i = 0; i < 4; ++i)
#pragma unroll
            for (int j = 0; j < 4; ++j)
                acc[i][j] = __builtin_amdgcn_mfma_f32_16x16x32_bf16(bfr[j], af[i], acc[i][j], 0, 0, 0);
    }

#pragma unroll
    for (int i = 0; i < 4; ++i) {
#pragma unroll
        for (int j = 0; j < 4; ++j) {
            const int rowg = m0 + wr * 64 + i * 16 + llo;
            const int colb = wc * 64 + j * 16 + lhi * 4;        // within tile
            const size_t idx = (size_t)rowg * ldo + (n0r + colb);
            bf16x4 o;
            if constexpr (EPI == EPI_BIAS) {
                f32x4 b4 = *(const f32x4*)(bias + n0 + colb);
#pragma unroll
                for (int r = 0; r < 4; ++r) o[r] = (__bf16)(acc[i][j][r] + b4[r]);
            } else if constexpr (EPI == EPI_RELU) {
#pragma unroll
                for (int r = 0; r < 4; ++r) o[r] = (__bf16)fmaxf(acc[i][j][r], 0.f);
            } else { // EPI_SUBR
                bf16x4 s4 = *(const bf16x4*)(subp + idx);
#pragma unroll
                for (int r = 0; r < 4; ++r) o[r] = (__bf16)fmaxf((float)s4[r] - acc[i][j][r], 0.f);
            }
            *(bf16x4*)(outp + idx) = o;
        }
    }
}

// ---------------------------------------------------------------------------
// Fused steps 7+8: K-loop 1280 = [0,512) pos | [512,1024) neg-1 | [1024,1280) neg-2
//   out_pos = 0.9*r_pos + 0.1*relu( (x-pred) - rpv2 @ Wpepos^T)
//   out_neg = 0.9*r_neg + 0.1*relu(-(x-pred) - rpv1 @ Wpeneg^T - rsom @ Wsomd^T)
// ---------------------------------------------------------------------------
__global__ __launch_bounds__(256)
void pe_filt_fused(const __bf16* __restrict__ Apos,   // rpv2  (B x 512)
                   const __bf16* __restrict__ Aneg1,  // rpv1  (B x 512)
                   const __bf16* __restrict__ Aneg2,  // rsom  (B x 256)
                   const __bf16* __restrict__ Wpos,   // 2048 x 512
                   const __bf16* __restrict__ Wneg1,  // 2048 x 512
                   const __bf16* __restrict__ Wneg2,  // 2048 x 256
                   const __bf16* __restrict__ xbf,
                   const __bf16* __restrict__ predb,
                   const float* __restrict__ rpos, const float* __restrict__ rneg,
                   float* __restrict__ outp, float* __restrict__ outn)
{
    GEMM_PREAMBLE(64)
    const int n0r = n0;

    const f32x4 fzero = {0.f, 0.f, 0.f, 0.f};
    f32x4 accP[4][4], accN[4][4];
#pragma unroll
    for (int i = 0; i < 4; ++i)
#pragma unroll
        for (int j = 0; j < 4; ++j) { accP[i][j] = fzero; accN[i][j] = fzero; }

    for (int k0 = 0; k0 < 1280; k0 += 32) {
        __syncthreads();
        if (k0 < 512) {
            STAGE_TILE(Apos, 512, Wpos, 512, k0)
        } else if (k0 < 1024) {
            STAGE_TILE(Aneg1, 512, Wneg1, 512, k0 - 512)
        } else {
            STAGE_TILE(Aneg2, 256, Wneg2, 256, k0 - 1024)
        }
        __syncthreads();
        bf16x8 af[4], bfr[4];
        LOAD_FRAGS(af, bfr)
        if (k0 < 512) {
#pragma unroll
            for (int i = 0; i < 4; ++i)
#pragma unroll
                for (int j = 0; j < 4; ++j)
                    accP[i][j] = __builtin_amdgcn_mfma_f32_16x16x32_bf16(bfr[j], af[i], accP[i][j], 0, 0, 0);
        } else {
#pragma unroll
            for (int i = 0; i < 4; ++i)
#pragma unroll
                for (int j = 0; j < 4; ++j)
                    accN[i][j] = __builtin_amdgcn_mfma_f32_16x16x32_bf16(bfr[j], af[i], accN[i][j], 0, 0, 0);
        }
    }

#pragma unroll
    for (int i = 0; i < 4; ++i) {
#pragma unroll
        for (int j = 0; j < 4; ++j) {
            const int rowg = m0 + wr * 64 + i * 16 + llo;
            const int colg = n0 + wc * 64 + j * 16 + lhi * 4;
            const size_t idx = (size_t)rowg * 2048 + colg;
            f32x4 rp = *(const f32x4*)(rpos + idx);
            f32x4 rn = *(const f32x4*)(rneg + idx);
            bf16x4 xb = *(const bf16x4*)(xbf + idx);
            bf16x4 pb = *(const bf16x4*)(predb + idx);
            f32x4 op, on;
#pragma unroll
            for (int r = 0; r < 4; ++r) {
                const float d = (float)xb[r] - (float)pb[r];
                op[r] = 0.9f * rp[r] + 0.1f * fmaxf( d - accP[i][j][r], 0.f);
                on[r] = 0.9f * rn[r] + 0.1f * fmaxf(-d - accN[i][j][r], 0.f);
            }
            *(f32x4*)(outp + idx) = op;
            *(f32x4*)(outn + idx) = on;
        }
    }
}

extern "C" void kernel_launch(void* const* d_in, const int* in_sizes, int n_in,
                              void* d_out, int out_size, void* d_ws, size_t ws_size,
                              hipStream_t stream) {
    (void)in_sizes; (void)n_in; (void)out_size; (void)ws_size;

    const float* x       = (const float*)d_in[0];
    const float* ctx     = (const float*)d_in[1];
    const float* r_pos   = (const float*)d_in[2];
    const float* r_neg   = (const float*)d_in[3];
    const float* Wpred   = (const float*)d_in[4];
    const float* bpred   = (const float*)d_in[5];
    const float* Wpv1    = (const float*)d_in[6];
    const float* Wpv2    = (const float*)d_in[7];
    const float* Wvip    = (const float*)d_in[8];
    const float* Wsomin  = (const float*)d_in[9];
    const float* Wvipsom = (const float*)d_in[10];
    const float* Wpepos  = (const float*)d_in[11];
    const float* Wpeneg  = (const float*)d_in[12];
    const float* Wsomd   = (const float*)d_in[13];

    char* ws = (char*)d_ws;
    __bf16* x_bf      = (__bf16*)ws; ws += (size_t)BV * DIMV * 2;
    __bf16* ctx_bf    = (__bf16*)ws; ws += (size_t)BV * CTXV * 2;
    __bf16* pred_bf   = (__bf16*)ws; ws += (size_t)BV * DIMV * 2;
    __bf16* rpv1_bf   = (__bf16*)ws; ws += (size_t)BV * NPV * 2;
    __bf16* rpv2_bf   = (__bf16*)ws; ws += (size_t)BV * NPV * 2;
    __bf16* rvip_bf   = (__bf16*)ws; ws += (size_t)BV * NSV * 2;
    __bf16* ssom_bf   = (__bf16*)ws; ws += (size_t)BV * NSV * 2;
    __bf16* rsom_bf   = (__bf16*)ws; ws += (size_t)BV * NSV * 2;
    __bf16* Wpred_bf  = (__bf16*)ws; ws += (size_t)DIMV * CTXV * 2;
    __bf16* Wpv1_bf   = (__bf16*)ws; ws += (size_t)NPV * DIMV * 2;
    __bf16* Wpv2_bf   = (__bf16*)ws; ws += (size_t)NPV * DIMV * 2;
    __bf16* Wvip_bf   = (__bf16*)ws; ws += (size_t)NSV * DIMV * 2;
    __bf16* Wsomin_bf = (__bf16*)ws; ws += (size_t)NSV * DIMV * 2;
    __bf16* Wvipsom_bf= (__bf16*)ws; ws += (size_t)NSV * NSV * 2;
    __bf16* Wpepos_bf = (__bf16*)ws; ws += (size_t)DIMV * NPV * 2;
    __bf16* Wpeneg_bf = (__bf16*)ws; ws += (size_t)DIMV * NPV * 2;
    __bf16* Wsomd_bf  = (__bf16*)ws; ws += (size_t)DIMV * NSV * 2;

    float* out_pos = (float*)d_out;
    float* out_neg = out_pos + (size_t)BV * DIMV;

    CvtArgs ca;
    ca.src[0] = x;       ca.dst[0] = x_bf;
    ca.src[1] = ctx;     ca.dst[1] = ctx_bf;
    ca.src[2] = Wpred;   ca.dst[2] = Wpred_bf;
    ca.src[3] = Wpv1;    ca.dst[3] = Wpv1_bf;
    ca.src[4] = Wpv2;    ca.dst[4] = Wpv2_bf;
    ca.src[5] = Wvip;    ca.dst[5] = Wvip_bf;
    ca.src[6] = Wsomin;  ca.dst[6] = Wsomin_bf;
    ca.src[7] = Wvipsom; ca.dst[7] = Wvipsom_bf;
    ca.src[8] = Wpepos;  ca.dst[8] = Wpepos_bf;
    ca.src[9] = Wpeneg;  ca.dst[9] = Wpeneg_bf;
    ca.src[10] = Wsomd;  ca.dst[10] = Wsomd_bf;
    cvt_all<<<dim3(2048), dim3(256), 0, stream>>>(ca);

    dim3 blk(256);

    // 1. pred_bf = bf16(ctx @ Wpred^T + b_pred)           (N=2048, K=512)
    pe_gemm<EPI_BIAS><<<dim3(1024), blk, 0, stream>>>(
        ctx_bf, CTXV, Wpred_bf, nullptr, CTXV,
        DIMV, DIMV, 0, CTXV, 64,
        bpred, nullptr, pred_bf, nullptr);

    // 2+3. [rpv1 | ssom] = relu(x @ [Wpv1 | Wsomin]^T)    (N=512+256, K=2048)
    pe_gemm<EPI_RELU><<<dim3(384), blk, 0, stream>>>(
        x_bf, DIMV, Wpv1_bf, Wsomin_bf, DIMV,
        NPV, NPV, NSV, DIMV, 64,
        nullptr, nullptr, rpv1_bf, ssom_bf);

    // 4+5. [rpv2 | rvip] = relu(pred @ [Wpv2 | Wvip]^T)   (N=512+256, K=2048)
    pe_gemm<EPI_RELU><<<dim3(384), blk, 0, stream>>>(
        pred_bf, DIMV, Wpv2_bf, Wvip_bf, DIMV,
        NPV, NPV, NSV, DIMV, 64,
        nullptr, nullptr, rpv2_bf, rvip_bf);

    // 6. rsom = relu(ssom - rvip @ Wvipsom^T)             (N=256, K=256)
    pe_gemm<EPI_SUBR><<<dim3(128), blk, 0, stream>>>(
        rvip_bf, NSV, Wvipsom_bf, nullptr, NSV,
        NSV, NSV, 0, NSV, 64,
        nullptr, ssom_bf, rsom_bf, nullptr);

    // 7+8 fused.
    pe_filt_fused<<<dim3(1024), blk, 0, stream>>>(
        rpv2_bf, rpv1_bf, rsom_bf,
        Wpepos_bf, Wpeneg_bf, Wsomd_bf,
        x_bf, pred_bf, r_pos, r_neg, out_pos, out_neg);
}

// Round 4
// 379.814 us; speedup vs baseline: 1.0392x; 1.0392x over previous
//
#include <hip/hip_runtime.h>
#include <hip/hip_bf16.h>
#include <stdint.h>
#include <stddef.h>

#define DIMV 2048
#define CTXV 512
#define BV   8192
#define NPV  512
#define NSV  256

typedef __attribute__((ext_vector_type(8))) __bf16 bf16x8;
typedef __attribute__((ext_vector_type(4))) __bf16 bf16x4;
typedef __attribute__((ext_vector_type(4))) float f32x4;

__device__ __forceinline__ void gload_lds16(const void* g, void* l) {
    __builtin_amdgcn_global_load_lds(
        (const __attribute__((address_space(1))) unsigned int*)g,
        (__attribute__((address_space(3))) unsigned int*)l,
        16, 0, 0);
}

// ---------------------------------------------------------------------------
// Batched fp32 -> bf16 convert (x, ctx, 9 weights)
// ---------------------------------------------------------------------------
struct CvtArgs {
    const float* src[11];
    __bf16*      dst[11];
};

__global__ __launch_bounds__(256) void cvt_all(CvtArgs a) {
    constexpr int NSEG = 11;
    constexpr unsigned cum[NSEG + 1] = {
        0u, 2097152u, 2621440u, 2752512u, 2883584u, 3014656u,
        3080192u, 3145728u, 3153920u, 3284992u, 3416064u, 3481600u};
    const unsigned total = cum[NSEG];
    for (unsigned c = blockIdx.x * blockDim.x + threadIdx.x; c < total;
         c += gridDim.x * blockDim.x) {
        const float* sp = a.src[0];
        __bf16*      dp = a.dst[0];
        unsigned     base = 0;
#pragma unroll
        for (int t = 1; t < NSEG; ++t) {
            const bool g = (c >= cum[t]);
            sp   = g ? a.src[t] : sp;
            dp   = g ? a.dst[t] : dp;
            base = g ? cum[t] : base;
        }
        const unsigned off = (c - base) * 8u;
        f32x4 v0 = *(const f32x4*)(sp + off);
        f32x4 v1 = *(const f32x4*)(sp + off + 4);
        bf16x8 o;
#pragma unroll
        for (int e = 0; e < 4; ++e) { o[e] = (__bf16)v0[e]; o[e + 4] = (__bf16)v1[e]; }
        *(bf16x8*)(dp + off) = o;
    }
}

// ---------------------------------------------------------------------------
// Descriptor-driven bf16 MFMA GEMM, 128x128 tile, BK=32, 4 waves (2x2),
// 16x16x32 MFMA, 2-PHASE double-buffered LDS:
//   prologue: STAGE(buf0, step0); barrier;
//   loop s:   STAGE(buf^1, s+1);  ds_read+MFMA from buf;  barrier; flip.
// __syncthreads() emits s_waitcnt vmcnt(0) lgkmcnt(0) + s_barrier, so the
// prefetch issued this step is guaranteed landed for the next step, and all
// ds_reads of the to-be-overwritten buffer completed before the flip.
// Staging: global_load_lds(16B), read-side XOR swizzle (chunk ^= (row>>1)&3)
// realized by pre-swizzling the GLOBAL source address (both-sides rule).
// MFMA operands SWAPPED: acc[i][j] = mfma(bfr[j], af[i], acc) so a lane's 4
// acc regs are 4 CONSECUTIVE OUTPUT COLS -> vectorized epilogues.
//   batch row = m0 + wr*64 + i*16 + (lane&15)
//   out col   = n0 + wc*64 + j*16 + (lane>>4)*4 + r        [harness-verified]
// Supports K-concat (A0/A1, W1/W1b split at ksplit) and N-concat (W2/out2
// at NB1). Two descriptors per launch, selected by block range.
// ---------------------------------------------------------------------------
struct GemmDesc {
    const __bf16* A0; const __bf16* A1; int ldA0, ldA1;
    const __bf16* W1; const __bf16* W2; const __bf16* W1b; int ldW, ldWb;
    int ksplit;          // K where A/W source switches (== K if none)
    int NB1;             // N-concat boundary (mult of 128; huge if none)
    int N1cols, N2cols;  // row strides of out1/out2
    int K;
    int epi;             // 0=bias->bf16, 1=relu->bf16(+region), 2=subr->bf16, 3=filt->f32
    const float* bias;
    const __bf16* subp;
    const __bf16* xbf; const __bf16* predb; const float* rold; float sgn;
    void* out1; void* out2;
};

__global__ __launch_bounds__(256)
void pe_gemm2(GemmDesc dA_, GemmDesc dB_, int splitWg)
{
    __shared__ __align__(16) char ldsA[2][8192];
    __shared__ __align__(16) char ldsB[2][8192];

    const int nwg = gridDim.x;
    const int bid = blockIdx.x;
    int wg = (bid & 7) * (nwg >> 3) + (bid >> 3);   // XCD-bijective (nwg%8==0)
    const bool second = (wg >= splitWg);
    if (second) wg -= splitWg;
    const GemmDesc d = second ? dB_ : dA_;

    const int bx = wg & 63;          // M tiles: 8192/128 = 64 always
    const int by = wg >> 6;
    const int m0 = bx * 128;
    const int n0 = by * 128;

    const bool reg2   = (n0 >= d.NB1);
    const __bf16* Wk0 = reg2 ? d.W2 : d.W1;
    const int n0r     = reg2 ? (n0 - d.NB1) : n0;

    const int tid  = threadIdx.x;
    const int wave = tid >> 6;
    const int lane = tid & 63;
    const int lhi  = lane >> 4;
    const int llo  = lane & 15;
    const int wr   = wave >> 1;
    const int wc   = wave & 1;
    const int rins = lane >> 2;
    const int ch   = lane & 3;

    const f32x4 fzero = {0.f, 0.f, 0.f, 0.f};
    f32x4 acc[4][4];
#pragma unroll
    for (int i = 0; i < 4; ++i)
#pragma unroll
        for (int j = 0; j < 4; ++j) acc[i][j] = fzero;

    const int nsteps = d.K >> 5;

#define STAGE2(S, BUF)                                                        \
    {                                                                         \
        const int k0_ = (S) * 32;                                             \
        const bool sg1 = (k0_ >= d.ksplit);                                   \
        const __bf16* As_ = sg1 ? d.A1  : d.A0;                               \
        const __bf16* Ws_ = sg1 ? d.W1b : Wk0;                                \
        const int la_ = sg1 ? d.ldA1 : d.ldA0;                                \
        const int lw_ = sg1 ? d.ldWb : d.ldW;                                 \
        const int kb_ = sg1 ? (k0_ - d.ksplit) : k0_;                         \
        _Pragma("unroll")                                                     \
        for (int half = 0; half < 2; ++half) {                                \
            const int rt = wave * 32 + half * 16 + rins;                      \
            const int kc = ch ^ ((rt >> 1) & 3);                              \
            const int kk = kb_ + kc * 8;                                      \
            gload_lds16(As_ + (size_t)(m0 + rt) * la_ + kk,                   \
                        ldsA[BUF] + wave * 2048 + half * 1024);               \
            gload_lds16(Ws_ + (size_t)(n0r + rt) * lw_ + kk,                  \
                        ldsB[BUF] + wave * 2048 + half * 1024);               \
        }                                                                     \
    }

    STAGE2(0, 0)
    __syncthreads();
    int cur = 0;
    for (int s = 0; s < nsteps; ++s) {
        if (s + 1 < nsteps) STAGE2(s + 1, cur ^ 1)
        bf16x8 af[4], bfr[4];
#pragma unroll
        for (int i = 0; i < 4; ++i) {
            const int r  = wr * 64 + i * 16 + llo;
            const int pc = lhi ^ ((r >> 1) & 3);
            af[i] = *(const bf16x8*)(ldsA[cur] + r * 64 + pc * 16);
        }
#pragma unroll
        for (int j = 0; j < 4; ++j) {
            const int r  = wc * 64 + j * 16 + llo;
            const int pc = lhi ^ ((r >> 1) & 3);
            bfr[j] = *(const bf16x8*)(ldsB[cur] + r * 64 + pc * 16);
        }
#pragma unroll
        for (int i = 0; i < 4; ++i)
#pragma unroll
            for (int j = 0; j < 4; ++j)
                acc[i][j] = __builtin_amdgcn_mfma_f32_16x16x32_bf16(bfr[j], af[i], acc[i][j], 0, 0, 0);
        __syncthreads();
        cur ^= 1;
    }
#undef STAGE2

#pragma unroll
    for (int i = 0; i < 4; ++i) {
#pragma unroll
        for (int j = 0; j < 4; ++j) {
            const int rowg = m0 + wr * 64 + i * 16 + llo;
            const int colb = wc * 64 + j * 16 + lhi * 4;
            if (d.epi == 0) {            // BIAS -> bf16
                const size_t idx = (size_t)rowg * d.N1cols + (n0 + colb);
                f32x4 b4 = *(const f32x4*)(d.bias + n0 + colb);
                bf16x4 o;
#pragma unroll
                for (int r = 0; r < 4; ++r) o[r] = (__bf16)(acc[i][j][r] + b4[r]);
                *(bf16x4*)((__bf16*)d.out1 + idx) = o;
            } else if (d.epi == 1) {     // RELU -> bf16, N-region
                __bf16* op   = reg2 ? (__bf16*)d.out2 : (__bf16*)d.out1;
                const int ldo = reg2 ? d.N2cols : d.N1cols;
                const size_t idx = (size_t)rowg * ldo + (n0r + colb);
                bf16x4 o;
#pragma unroll
                for (int r = 0; r < 4; ++r) o[r] = (__bf16)fmaxf(acc[i][j][r], 0.f);
                *(bf16x4*)(op + idx) = o;
            } else if (d.epi == 2) {     // SUBR: relu(subp - acc) -> bf16
                const size_t idx = (size_t)rowg * d.N1cols + (n0 + colb);
                bf16x4 s4 = *(const bf16x4*)(d.subp + idx);
                bf16x4 o;
#pragma unroll
                for (int r = 0; r < 4; ++r)
                    o[r] = (__bf16)fmaxf((float)s4[r] - acc[i][j][r], 0.f);
                *(bf16x4*)((__bf16*)d.out1 + idx) = o;
            } else {                     // FILT -> f32
                const size_t idx = (size_t)rowg * 2048 + (n0 + colb);
                f32x4 rp  = *(const f32x4*)(d.rold + idx);
                bf16x4 xb = *(const bf16x4*)(d.xbf + idx);
                bf16x4 pb = *(const bf16x4*)(d.predb + idx);
                f32x4 o;
#pragma unroll
                for (int r = 0; r < 4; ++r) {
                    const float dd = d.sgn * ((float)xb[r] - (float)pb[r]);
                    o[r] = 0.9f * rp[r] + 0.1f * fmaxf(dd - acc[i][j][r], 0.f);
                }
                *(f32x4*)((float*)d.out1 + idx) = o;
            }
        }
    }
}

extern "C" void kernel_launch(void* const* d_in, const int* in_sizes, int n_in,
                              void* d_out, int out_size, void* d_ws, size_t ws_size,
                              hipStream_t stream) {
    (void)in_sizes; (void)n_in; (void)out_size; (void)ws_size;

    const float* x       = (const float*)d_in[0];
    const float* ctx     = (const float*)d_in[1];
    const float* r_pos   = (const float*)d_in[2];
    const float* r_neg   = (const float*)d_in[3];
    const float* Wpred   = (const float*)d_in[4];
    const float* bpred   = (const float*)d_in[5];
    const float* Wpv1    = (const float*)d_in[6];
    const float* Wpv2    = (const float*)d_in[7];
    const float* Wvip    = (const float*)d_in[8];
    const float* Wsomin  = (const float*)d_in[9];
    const float* Wvipsom = (const float*)d_in[10];
    const float* Wpepos  = (const float*)d_in[11];
    const float* Wpeneg  = (const float*)d_in[12];
    const float* Wsomd   = (const float*)d_in[13];

    char* ws = (char*)d_ws;
    __bf16* x_bf      = (__bf16*)ws; ws += (size_t)BV * DIMV * 2;
    __bf16* ctx_bf    = (__bf16*)ws; ws += (size_t)BV * CTXV * 2;
    __bf16* pred_bf   = (__bf16*)ws; ws += (size_t)BV * DIMV * 2;
    __bf16* rpv1_bf   = (__bf16*)ws; ws += (size_t)BV * NPV * 2;
    __bf16* rpv2_bf   = (__bf16*)ws; ws += (size_t)BV * NPV * 2;
    __bf16* rvip_bf   = (__bf16*)ws; ws += (size_t)BV * NSV * 2;
    __bf16* ssom_bf   = (__bf16*)ws; ws += (size_t)BV * NSV * 2;
    __bf16* rsom_bf   = (__bf16*)ws; ws += (size_t)BV * NSV * 2;
    __bf16* Wpred_bf  = (__bf16*)ws; ws += (size_t)DIMV * CTXV * 2;
    __bf16* Wpv1_bf   = (__bf16*)ws; ws += (size_t)NPV * DIMV * 2;
    __bf16* Wpv2_bf   = (__bf16*)ws; ws += (size_t)NPV * DIMV * 2;
    __bf16* Wvip_bf   = (__bf16*)ws; ws += (size_t)NSV * DIMV * 2;
    __bf16* Wsomin_bf = (__bf16*)ws; ws += (size_t)NSV * DIMV * 2;
    __bf16* Wvipsom_bf= (__bf16*)ws; ws += (size_t)NSV * NSV * 2;
    __bf16* Wpepos_bf = (__bf16*)ws; ws += (size_t)DIMV * NPV * 2;
    __bf16* Wpeneg_bf = (__bf16*)ws; ws += (size_t)DIMV * NPV * 2;
    __bf16* Wsomd_bf  = (__bf16*)ws; ws += (size_t)DIMV * NSV * 2;

    float* out_pos = (float*)d_out;
    float* out_neg = out_pos + (size_t)BV * DIMV;

    CvtArgs ca;
    ca.src[0] = x;       ca.dst[0] = x_bf;
    ca.src[1] = ctx;     ca.dst[1] = ctx_bf;
    ca.src[2] = Wpred;   ca.dst[2] = Wpred_bf;
    ca.src[3] = Wpv1;    ca.dst[3] = Wpv1_bf;
    ca.src[4] = Wpv2;    ca.dst[4] = Wpv2_bf;
    ca.src[5] = Wvip;    ca.dst[5] = Wvip_bf;
    ca.src[6] = Wsomin;  ca.dst[6] = Wsomin_bf;
    ca.src[7] = Wvipsom; ca.dst[7] = Wvipsom_bf;
    ca.src[8] = Wpepos;  ca.dst[8] = Wpepos_bf;
    ca.src[9] = Wpeneg;  ca.dst[9] = Wpeneg_bf;
    ca.src[10] = Wsomd;  ca.dst[10] = Wsomd_bf;
    cvt_all<<<dim3(2048), dim3(256), 0, stream>>>(ca);

    const int BIG = 1 << 28;
    GemmDesc dz; // zero-ish template
    dz.A0 = dz.A1 = nullptr; dz.ldA0 = dz.ldA1 = 0;
    dz.W1 = dz.W2 = dz.W1b = nullptr; dz.ldW = dz.ldWb = 0;
    dz.ksplit = BIG; dz.NB1 = BIG; dz.N1cols = dz.N2cols = 0; dz.K = 32;
    dz.epi = 1; dz.bias = nullptr; dz.subp = nullptr;
    dz.xbf = dz.predb = nullptr; dz.rold = nullptr; dz.sgn = 1.f;
    dz.out1 = dz.out2 = nullptr;

    // L1: pred (1024 blocks) || 2+3 (384 blocks)
    GemmDesc d_pred = dz;
    d_pred.A0 = ctx_bf; d_pred.A1 = ctx_bf; d_pred.ldA0 = d_pred.ldA1 = CTXV;
    d_pred.W1 = d_pred.W2 = d_pred.W1b = Wpred_bf; d_pred.ldW = d_pred.ldWb = CTXV;
    d_pred.K = CTXV; d_pred.N1cols = DIMV; d_pred.epi = 0;
    d_pred.bias = bpred; d_pred.out1 = pred_bf;

    GemmDesc d_23 = dz;
    d_23.A0 = d_23.A1 = x_bf; d_23.ldA0 = d_23.ldA1 = DIMV;
    d_23.W1 = Wpv1_bf; d_23.W2 = Wsomin_bf; d_23.W1b = Wpv1_bf;
    d_23.ldW = d_23.ldWb = DIMV;
    d_23.K = DIMV; d_23.NB1 = NPV; d_23.N1cols = NPV; d_23.N2cols = NSV;
    d_23.epi = 1; d_23.out1 = rpv1_bf; d_23.out2 = ssom_bf;

    pe_gemm2<<<dim3(1408), dim3(256), 0, stream>>>(d_pred, d_23, 1024);

    // L2: 4+5 (384 blocks)
    GemmDesc d_45 = dz;
    d_45.A0 = d_45.A1 = pred_bf; d_45.ldA0 = d_45.ldA1 = DIMV;
    d_45.W1 = Wpv2_bf; d_45.W2 = Wvip_bf; d_45.W1b = Wpv2_bf;
    d_45.ldW = d_45.ldWb = DIMV;
    d_45.K = DIMV; d_45.NB1 = NPV; d_45.N1cols = NPV; d_45.N2cols = NSV;
    d_45.epi = 1; d_45.out1 = rpv2_bf; d_45.out2 = rvip_bf;

    pe_gemm2<<<dim3(384), dim3(256), 0, stream>>>(d_45, d_45, 384);

    // L3: rsom (128 blocks)
    GemmDesc d_som = dz;
    d_som.A0 = d_som.A1 = rvip_bf; d_som.ldA0 = d_som.ldA1 = NSV;
    d_som.W1 = d_som.W2 = d_som.W1b = Wvipsom_bf; d_som.ldW = d_som.ldWb = NSV;
    d_som.K = NSV; d_som.N1cols = NSV; d_som.epi = 2;
    d_som.subp = ssom_bf; d_som.out1 = rsom_bf;

    pe_gemm2<<<dim3(128), dim3(256), 0, stream>>>(d_som, d_som, 128);

    // L4: filt7 (1024) || filt8 (1024, K-concat 512+256)
    GemmDesc d_f7 = dz;
    d_f7.A0 = d_f7.A1 = rpv2_bf; d_f7.ldA0 = d_f7.ldA1 = NPV;
    d_f7.W1 = d_f7.W2 = d_f7.W1b = Wpepos_bf; d_f7.ldW = d_f7.ldWb = NPV;
    d_f7.K = NPV; d_f7.N1cols = DIMV; d_f7.epi = 3;
    d_f7.xbf = x_bf; d_f7.predb = pred_bf; d_f7.rold = r_pos; d_f7.sgn = 1.f;
    d_f7.out1 = out_pos;

    GemmDesc d_f8 = dz;
    d_f8.A0 = rpv1_bf; d_f8.A1 = rsom_bf; d_f8.ldA0 = NPV; d_f8.ldA1 = NSV;
    d_f8.W1 = d_f8.W2 = Wpeneg_bf; d_f8.W1b = Wsomd_bf;
    d_f8.ldW = NPV; d_f8.ldWb = NSV; d_f8.ksplit = NPV;
    d_f8.K = NPV + NSV; d_f8.N1cols = DIMV; d_f8.epi = 3;
    d_f8.xbf = x_bf; d_f8.predb = pred_bf; d_f8.rold = r_neg; d_f8.sgn = -1.f;
    d_f8.out1 = out_neg;

    pe_gemm2<<<dim3(2048), dim3(256), 0, stream>>>(d_f7, d_f8, 1024);
}

// Round 5
// 374.110 us; speedup vs baseline: 1.0550x; 1.0152x over previous
//
#include <hip/hip_runtime.h>
#include <hip/hip_bf16.h>
#include <stdint.h>
#include <stddef.h>

#define DIMV 2048
#define CTXV 512
#define BV   8192
#define NPV  512
#define NSV  256

typedef __attribute__((ext_vector_type(8))) __bf16 bf16x8;
typedef __attribute__((ext_vector_type(4))) __bf16 bf16x4;
typedef __attribute__((ext_vector_type(4))) float f32x4;

__device__ __forceinline__ void gload_lds16(const void* g, void* l) {
    __builtin_amdgcn_global_load_lds(
        (const __attribute__((address_space(1))) unsigned int*)g,
        (__attribute__((address_space(3))) unsigned int*)l,
        16, 0, 0);
}

// ---------------------------------------------------------------------------
// Batched fp32 -> bf16 convert (x, ctx, 9 weights)
// ---------------------------------------------------------------------------
struct CvtArgs {
    const float* src[11];
    __bf16*      dst[11];
};

__global__ __launch_bounds__(256) void cvt_all(CvtArgs a) {
    constexpr int NSEG = 11;
    constexpr unsigned cum[NSEG + 1] = {
        0u, 2097152u, 2621440u, 2752512u, 2883584u, 3014656u,
        3080192u, 3145728u, 3153920u, 3284992u, 3416064u, 3481600u};
    const unsigned total = cum[NSEG];
    for (unsigned c = blockIdx.x * blockDim.x + threadIdx.x; c < total;
         c += gridDim.x * blockDim.x) {
        const float* sp = a.src[0];
        __bf16*      dp = a.dst[0];
        unsigned     base = 0;
#pragma unroll
        for (int t = 1; t < NSEG; ++t) {
            const bool g = (c >= cum[t]);
            sp   = g ? a.src[t] : sp;
            dp   = g ? a.dst[t] : dp;
            base = g ? cum[t] : base;
        }
        const unsigned off = (c - base) * 8u;
        f32x4 v0 = *(const f32x4*)(sp + off);
        f32x4 v1 = *(const f32x4*)(sp + off + 4);
        bf16x8 o;
#pragma unroll
        for (int e = 0; e < 4; ++e) { o[e] = (__bf16)v0[e]; o[e + 4] = (__bf16)v1[e]; }
        *(bf16x8*)(dp + off) = o;
    }
}

// ---------------------------------------------------------------------------
// 256x128 tile, BK=32, 8 waves (4x2 of 64x64), 512 threads, 16x16x32 MFMA,
// 2-phase double-buffered LDS (prologue stage; loop: stage-next, compute,
// barrier, flip). Staging via global_load_lds(16B); read-side XOR swizzle
// (chunk ^= (row>>1)&3) realized by pre-swizzling the GLOBAL source address.
// MFMA operands SWAPPED: acc[i][j] = mfma(bfr[j], af[i], acc):
//   batch row = m0 + wr*64 + i*16 + (lane&15)
//   out col   = n0 + wc*64 + j*16 + (lane>>4)*4 + r        [harness-verified]
// A-tile: 256 rows x 64B = 16KB/buf (16 stage insts: q = wave + h*8)
// B-tile: 128 rows x 64B =  8KB/buf (8 stage insts:  q = wave)
// ---------------------------------------------------------------------------
#define GEOM_PREAMBLE                                             \
    const int tid  = threadIdx.x;                                 \
    const int wave = tid >> 6;                                    \
    const int lane = tid & 63;                                    \
    const int lhi  = lane >> 4;                                   \
    const int llo  = lane & 15;                                   \
    const int wr   = wave >> 1;                                   \
    const int wc   = wave & 1;                                    \
    const int rins = lane >> 2;                                   \
    const int ch   = lane & 3;

#define LOAD_FRAGS3(BUF, af, bfr)                                     \
    _Pragma("unroll")                                                 \
    for (int i = 0; i < 4; ++i) {                                     \
        const int r  = wr * 64 + i * 16 + llo;                        \
        const int pc = lhi ^ ((r >> 1) & 3);                          \
        af[i] = *(const bf16x8*)(ldsA[BUF] + r * 64 + pc * 16);       \
    }                                                                 \
    _Pragma("unroll")                                                 \
    for (int j = 0; j < 4; ++j) {                                     \
        const int r  = wc * 64 + j * 16 + llo;                        \
        const int pc = lhi ^ ((r >> 1) & 3);                          \
        bfr[j] = *(const bf16x8*)(ldsB[BUF] + r * 64 + pc * 16);      \
    }

#define MFMA_ALL(af, bfr, acc)                                                        \
    _Pragma("unroll")                                                                 \
    for (int i = 0; i < 4; ++i)                                                       \
        _Pragma("unroll")                                                             \
        for (int j = 0; j < 4; ++j)                                                   \
            acc[i][j] = __builtin_amdgcn_mfma_f32_16x16x32_bf16(bfr[j], af[i], acc[i][j], 0, 0, 0);

// ---------------------------------------------------------------------------
// Generic descriptor GEMM (L1/L2/L3): two descriptors per launch by range.
// ---------------------------------------------------------------------------
struct GemmDesc {
    const __bf16* A0; int ldA0;
    const __bf16* W1; const __bf16* W2; int ldW;
    int NB1;             // N-concat boundary (mult of 128; huge if none)
    int N1cols, N2cols;  // row strides of out1/out2
    int K;
    int epi;             // 0=bias->bf16, 1=relu->bf16(+region), 2=subr->bf16
    const float* bias;
    const __bf16* subp;
    void* out1; void* out2;
};

__global__ __launch_bounds__(512)
void pe_gemm3(GemmDesc dA_, GemmDesc dB_, int splitWg)
{
    __shared__ __align__(16) char ldsA[2][16384];
    __shared__ __align__(16) char ldsB[2][8192];

    const int nwg = gridDim.x;
    const int bid = blockIdx.x;
    int wg = (bid & 7) * (nwg >> 3) + (bid >> 3);   // XCD-bijective (nwg%8==0)
    const bool second = (wg >= splitWg);
    if (second) wg -= splitWg;
    const GemmDesc d = second ? dB_ : dA_;

    const int bx = wg & 31;          // 8192/256 = 32 M-tiles
    const int by = wg >> 5;
    const int m0 = bx * 256;
    const int n0 = by * 128;

    const bool reg2   = (n0 >= d.NB1);
    const __bf16* Wc  = reg2 ? d.W2 : d.W1;
    const int n0r     = reg2 ? (n0 - d.NB1) : n0;

    GEOM_PREAMBLE

    const f32x4 fzero = {0.f, 0.f, 0.f, 0.f};
    f32x4 acc[4][4];
#pragma unroll
    for (int i = 0; i < 4; ++i)
#pragma unroll
        for (int j = 0; j < 4; ++j) acc[i][j] = fzero;

    const int nsteps = d.K >> 5;

#define STAGE_G(S, BUF)                                                       \
    {                                                                         \
        const int kb_ = (S) * 32;                                             \
        _Pragma("unroll")                                                     \
        for (int h = 0; h < 2; ++h) {                                         \
            const int q   = wave + h * 8;                                     \
            const int row = q * 16 + rins;                                    \
            const int kc  = ch ^ ((row >> 1) & 3);                            \
            gload_lds16(d.A0 + (size_t)(m0 + row) * d.ldA0 + kb_ + kc * 8,    \
                        ldsA[BUF] + q * 1024);                                \
        }                                                                     \
        {                                                                     \
            const int rowb = wave * 16 + rins;                                \
            const int kcb  = ch ^ ((rowb >> 1) & 3);                          \
            gload_lds16(Wc + (size_t)(n0r + rowb) * d.ldW + kb_ + kcb * 8,    \
                        ldsB[BUF] + wave * 1024);                             \
        }                                                                     \
    }

    STAGE_G(0, 0)
    __syncthreads();
    int cur = 0;
    for (int s = 0; s < nsteps; ++s) {
        if (s + 1 < nsteps) STAGE_G(s + 1, cur ^ 1)
        bf16x8 af[4], bfr[4];
        LOAD_FRAGS3(cur, af, bfr)
        MFMA_ALL(af, bfr, acc)
        __syncthreads();
        cur ^= 1;
    }
#undef STAGE_G

#pragma unroll
    for (int i = 0; i < 4; ++i) {
#pragma unroll
        for (int j = 0; j < 4; ++j) {
            const int rowg = m0 + wr * 64 + i * 16 + llo;
            const int colb = wc * 64 + j * 16 + lhi * 4;
            if (d.epi == 0) {            // BIAS -> bf16
                const size_t idx = (size_t)rowg * d.N1cols + (n0 + colb);
                f32x4 b4 = *(const f32x4*)(d.bias + n0 + colb);
                bf16x4 o;
#pragma unroll
                for (int r = 0; r < 4; ++r) o[r] = (__bf16)(acc[i][j][r] + b4[r]);
                *(bf16x4*)((__bf16*)d.out1 + idx) = o;
            } else if (d.epi == 1) {     // RELU -> bf16, N-region
                __bf16* op    = reg2 ? (__bf16*)d.out2 : (__bf16*)d.out1;
                const int ldo = reg2 ? d.N2cols : d.N1cols;
                const size_t idx = (size_t)rowg * ldo + (n0r + colb);
                bf16x4 o;
#pragma unroll
                for (int r = 0; r < 4; ++r) o[r] = (__bf16)fmaxf(acc[i][j][r], 0.f);
                *(bf16x4*)(op + idx) = o;
            } else {                     // SUBR: relu(subp - acc) -> bf16
                const size_t idx = (size_t)rowg * d.N1cols + (n0 + colb);
                bf16x4 s4 = *(const bf16x4*)(d.subp + idx);
                bf16x4 o;
#pragma unroll
                for (int r = 0; r < 4; ++r)
                    o[r] = (__bf16)fmaxf((float)s4[r] - acc[i][j][r], 0.f);
                *(bf16x4*)((__bf16*)d.out1 + idx) = o;
            }
        }
    }
}

// ---------------------------------------------------------------------------
// Merged FILT kernel (steps 7+8), sequential pos then neg, acc regs reused:
//   out_pos = 0.9*r_pos + 0.1*relu( (x-pred) - rpv2 @ Wpepos^T)
//   out_neg = 0.9*r_neg + 0.1*relu( (pred-x) - rpv1 @ Wpeneg^T - rsom @ Wsomd^T)
// First neg prefetch is issued BEFORE the pos epilogue (hides HBM latency).
// ---------------------------------------------------------------------------
__global__ __launch_bounds__(512)
void pe_filt3(const __bf16* __restrict__ rpv2, const __bf16* __restrict__ Wpepos,
              const __bf16* __restrict__ rpv1, const __bf16* __restrict__ rsom,
              const __bf16* __restrict__ Wpeneg, const __bf16* __restrict__ Wsomd,
              const __bf16* __restrict__ xbf, const __bf16* __restrict__ predb,
              const float* __restrict__ rpos, const float* __restrict__ rneg,
              float* __restrict__ outp, float* __restrict__ outn)
{
    __shared__ __align__(16) char ldsA[2][16384];
    __shared__ __align__(16) char ldsB[2][8192];

    const int nwg = gridDim.x;
    const int bid = blockIdx.x;
    const int wg  = (bid & 7) * (nwg >> 3) + (bid >> 3);
    const int bx  = wg & 31;
    const int by  = wg >> 5;
    const int m0  = bx * 256;
    const int n0  = by * 128;

    GEOM_PREAMBLE

#define STAGE_F(Asrc, ldA, Wsrc, ldW, KB, BUF)                                \
    {                                                                         \
        _Pragma("unroll")                                                     \
        for (int h = 0; h < 2; ++h) {                                         \
            const int q   = wave + h * 8;                                     \
            const int row = q * 16 + rins;                                    \
            const int kc  = ch ^ ((row >> 1) & 3);                            \
            gload_lds16((Asrc) + (size_t)(m0 + row) * (ldA) + (KB) + kc * 8,  \
                        ldsA[BUF] + q * 1024);                                \
        }                                                                     \
        {                                                                     \
            const int rowb = wave * 16 + rins;                                \
            const int kcb  = ch ^ ((rowb >> 1) & 3);                          \
            gload_lds16((Wsrc) + (size_t)(n0 + rowb) * (ldW) + (KB) + kcb * 8,\
                        ldsB[BUF] + wave * 1024);                             \
        }                                                                     \
    }

    const f32x4 fzero = {0.f, 0.f, 0.f, 0.f};
    f32x4 acc[4][4];
#pragma unroll
    for (int i = 0; i < 4; ++i)
#pragma unroll
        for (int j = 0; j < 4; ++j) acc[i][j] = fzero;

    // ---- POS K-loop (K=512, 16 steps) ----
    STAGE_F(rpv2, NPV, Wpepos, NPV, 0, 0)
    __syncthreads();
    int cur = 0;
    for (int s = 0; s < 16; ++s) {
        if (s + 1 < 16) STAGE_F(rpv2, NPV, Wpepos, NPV, (s + 1) * 32, cur ^ 1)
        bf16x8 af[4], bfr[4];
        LOAD_FRAGS3(cur, af, bfr)
        MFMA_ALL(af, bfr, acc)
        __syncthreads();
        cur ^= 1;
    }
    // cur == 0 here; both buffers free. Prefetch first NEG tile now.
    STAGE_F(rpv1, NPV, Wpeneg, NPV, 0, cur)

    // ---- POS epilogue ----
#pragma unroll
    for (int i = 0; i < 4; ++i) {
#pragma unroll
        for (int j = 0; j < 4; ++j) {
            const int rowg = m0 + wr * 64 + i * 16 + llo;
            const int colg = n0 + wc * 64 + j * 16 + lhi * 4;
            const size_t idx = (size_t)rowg * 2048 + colg;
            f32x4 rp  = *(const f32x4*)(rpos + idx);
            bf16x4 xb = *(const bf16x4*)(xbf + idx);
            bf16x4 pb = *(const bf16x4*)(predb + idx);
            f32x4 o;
#pragma unroll
            for (int r = 0; r < 4; ++r) {
                const float dd = (float)xb[r] - (float)pb[r];
                o[r] = 0.9f * rp[r] + 0.1f * fmaxf(dd - acc[i][j][r], 0.f);
            }
            *(f32x4*)(outp + idx) = o;
        }
    }
    __syncthreads();   // drains prefetch; all waves past pos phase

    // ---- NEG K-loop (K=768 = 512 rpv1/Wpeneg + 256 rsom/Wsomd, 24 steps) ----
#pragma unroll
    for (int i = 0; i < 4; ++i)
#pragma unroll
        for (int j = 0; j < 4; ++j) acc[i][j] = fzero;

    for (int s = 0; s < 24; ++s) {
        if (s + 1 < 24) {
            const int k0n = (s + 1) * 32;
            if (k0n < 512) {
                STAGE_F(rpv1, NPV, Wpeneg, NPV, k0n, cur ^ 1)
            } else {
                STAGE_F(rsom, NSV, Wsomd, NSV, k0n - 512, cur ^ 1)
            }
        }
        bf16x8 af[4], bfr[4];
        LOAD_FRAGS3(cur, af, bfr)
        MFMA_ALL(af, bfr, acc)
        __syncthreads();
        cur ^= 1;
    }

    // ---- NEG epilogue ----
#pragma unroll
    for (int i = 0; i < 4; ++i) {
#pragma unroll
        for (int j = 0; j < 4; ++j) {
            const int rowg = m0 + wr * 64 + i * 16 + llo;
            const int colg = n0 + wc * 64 + j * 16 + lhi * 4;
            const size_t idx = (size_t)rowg * 2048 + colg;
            f32x4 rn  = *(const f32x4*)(rneg + idx);
            bf16x4 xb = *(const bf16x4*)(xbf + idx);
            bf16x4 pb = *(const bf16x4*)(predb + idx);
            f32x4 o;
#pragma unroll
            for (int r = 0; r < 4; ++r) {
                const float dd = (float)pb[r] - (float)xb[r];
                o[r] = 0.9f * rn[r] + 0.1f * fmaxf(dd - acc[i][j][r], 0.f);
            }
            *(f32x4*)(outn + idx) = o;
        }
    }
#undef STAGE_F
}

extern "C" void kernel_launch(void* const* d_in, const int* in_sizes, int n_in,
                              void* d_out, int out_size, void* d_ws, size_t ws_size,
                              hipStream_t stream) {
    (void)in_sizes; (void)n_in; (void)out_size; (void)ws_size;

    const float* x       = (const float*)d_in[0];
    const float* ctx     = (const float*)d_in[1];
    const float* r_pos   = (const float*)d_in[2];
    const float* r_neg   = (const float*)d_in[3];
    const float* Wpred   = (const float*)d_in[4];
    const float* bpred   = (const float*)d_in[5];
    const float* Wpv1    = (const float*)d_in[6];
    const float* Wpv2    = (const float*)d_in[7];
    const float* Wvip    = (const float*)d_in[8];
    const float* Wsomin  = (const float*)d_in[9];
    const float* Wvipsom = (const float*)d_in[10];
    const float* Wpepos  = (const float*)d_in[11];
    const float* Wpeneg  = (const float*)d_in[12];
    const float* Wsomd   = (const float*)d_in[13];

    char* ws = (char*)d_ws;
    __bf16* x_bf      = (__bf16*)ws; ws += (size_t)BV * DIMV * 2;
    __bf16* ctx_bf    = (__bf16*)ws; ws += (size_t)BV * CTXV * 2;
    __bf16* pred_bf   = (__bf16*)ws; ws += (size_t)BV * DIMV * 2;
    __bf16* rpv1_bf   = (__bf16*)ws; ws += (size_t)BV * NPV * 2;
    __bf16* rpv2_bf   = (__bf16*)ws; ws += (size_t)BV * NPV * 2;
    __bf16* rvip_bf   = (__bf16*)ws; ws += (size_t)BV * NSV * 2;
    __bf16* ssom_bf   = (__bf16*)ws; ws += (size_t)BV * NSV * 2;
    __bf16* rsom_bf   = (__bf16*)ws; ws += (size_t)BV * NSV * 2;
    __bf16* Wpred_bf  = (__bf16*)ws; ws += (size_t)DIMV * CTXV * 2;
    __bf16* Wpv1_bf   = (__bf16*)ws; ws += (size_t)NPV * DIMV * 2;
    __bf16* Wpv2_bf   = (__bf16*)ws; ws += (size_t)NPV * DIMV * 2;
    __bf16* Wvip_bf   = (__bf16*)ws; ws += (size_t)NSV * DIMV * 2;
    __bf16* Wsomin_bf = (__bf16*)ws; ws += (size_t)NSV * DIMV * 2;
    __bf16* Wvipsom_bf= (__bf16*)ws; ws += (size_t)NSV * NSV * 2;
    __bf16* Wpepos_bf = (__bf16*)ws; ws += (size_t)DIMV * NPV * 2;
    __bf16* Wpeneg_bf = (__bf16*)ws; ws += (size_t)DIMV * NPV * 2;
    __bf16* Wsomd_bf  = (__bf16*)ws; ws += (size_t)DIMV * NSV * 2;

    float* out_pos = (float*)d_out;
    float* out_neg = out_pos + (size_t)BV * DIMV;

    CvtArgs ca;
    ca.src[0] = x;       ca.dst[0] = x_bf;
    ca.src[1] = ctx;     ca.dst[1] = ctx_bf;
    ca.src[2] = Wpred;   ca.dst[2] = Wpred_bf;
    ca.src[3] = Wpv1;    ca.dst[3] = Wpv1_bf;
    ca.src[4] = Wpv2;    ca.dst[4] = Wpv2_bf;
    ca.src[5] = Wvip;    ca.dst[5] = Wvip_bf;
    ca.src[6] = Wsomin;  ca.dst[6] = Wsomin_bf;
    ca.src[7] = Wvipsom; ca.dst[7] = Wvipsom_bf;
    ca.src[8] = Wpepos;  ca.dst[8] = Wpepos_bf;
    ca.src[9] = Wpeneg;  ca.dst[9] = Wpeneg_bf;
    ca.src[10] = Wsomd;  ca.dst[10] = Wsomd_bf;
    cvt_all<<<dim3(2048), dim3(256), 0, stream>>>(ca);

    const int BIG = 1 << 28;
    GemmDesc dz;
    dz.A0 = nullptr; dz.ldA0 = 0;
    dz.W1 = dz.W2 = nullptr; dz.ldW = 0;
    dz.NB1 = BIG; dz.N1cols = dz.N2cols = 0; dz.K = 32;
    dz.epi = 1; dz.bias = nullptr; dz.subp = nullptr;
    dz.out1 = dz.out2 = nullptr;

    // L1: pred (512 blocks) || 2+3 (192 blocks)
    GemmDesc d_pred = dz;
    d_pred.A0 = ctx_bf; d_pred.ldA0 = CTXV;
    d_pred.W1 = d_pred.W2 = Wpred_bf; d_pred.ldW = CTXV;
    d_pred.K = CTXV; d_pred.N1cols = DIMV; d_pred.epi = 0;
    d_pred.bias = bpred; d_pred.out1 = pred_bf;

    GemmDesc d_23 = dz;
    d_23.A0 = x_bf; d_23.ldA0 = DIMV;
    d_23.W1 = Wpv1_bf; d_23.W2 = Wsomin_bf; d_23.ldW = DIMV;
    d_23.K = DIMV; d_23.NB1 = NPV; d_23.N1cols = NPV; d_23.N2cols = NSV;
    d_23.epi = 1; d_23.out1 = rpv1_bf; d_23.out2 = ssom_bf;

    pe_gemm3<<<dim3(704), dim3(512), 0, stream>>>(d_pred, d_23, 512);

    // L2: 4+5 (192 blocks)
    GemmDesc d_45 = dz;
    d_45.A0 = pred_bf; d_45.ldA0 = DIMV;
    d_45.W1 = Wpv2_bf; d_45.W2 = Wvip_bf; d_45.ldW = DIMV;
    d_45.K = DIMV; d_45.NB1 = NPV; d_45.N1cols = NPV; d_45.N2cols = NSV;
    d_45.epi = 1; d_45.out1 = rpv2_bf; d_45.out2 = rvip_bf;

    pe_gemm3<<<dim3(192), dim3(512), 0, stream>>>(d_45, d_45, 192);

    // L3: rsom (64 blocks)
    GemmDesc d_som = dz;
    d_som.A0 = rvip_bf; d_som.ldA0 = NSV;
    d_som.W1 = d_som.W2 = Wvipsom_bf; d_som.ldW = NSV;
    d_som.K = NSV; d_som.N1cols = NSV; d_som.epi = 2;
    d_som.subp = ssom_bf; d_som.out1 = rsom_bf;

    pe_gemm3<<<dim3(64), dim3(512), 0, stream>>>(d_som, d_som, 64);

    // L4: merged filt (512 blocks)
    pe_filt3<<<dim3(512), dim3(512), 0, stream>>>(
        rpv2_bf, Wpepos_bf, rpv1_bf, rsom_bf, Wpeneg_bf, Wsomd_bf,
        x_bf, pred_bf, r_pos, r_neg, out_pos, out_neg);
}